// Round 8
// baseline (42.400 us; speedup 1.0000x reference)
//
#include <hip/hip_runtime.h>
#include <hip/hip_bf16.h>
#include <stdint.h>

// KANLinear: y[b,o] = sum_{d,k} coeff[b,d,k]*values[o,d,k] + xc@skip_w^T + skip_b
//   Vp[o,d*16+k] = values[o,d,k] + grid[k]*skip_w[o,d]   (prep, bf16)
//   y = A @ Vp^T + skip_b  (MFMA GEMM  M=8192 N=256 K=4096)
// Round 8: BARRIER-FREE K-loop. A-fragments built in registers from a 64KB
//          per-block Pk table (packed {shifted bf16 pair, jl}, built once);
//          no LDS writes / no lgkm drains / no s_barrier in the main loop ->
//          waves free-run and the shared MFMA queue self-schedules.
//          B direct from L2 (chunk-transposed Vp), 1-deep reg prefetch.
//          KS=4, BM=128, BN=128, grid 512 (2 blocks/CU), partials + reduce.

#define D_DIM  256
#define O_DIM  256
#define BM     128
#define NTHR   256

typedef __attribute__((ext_vector_type(8))) short bf16x8;
typedef __attribute__((ext_vector_type(4))) float f32x4;

// ---------------------------------------------------------------------------
// Prep: Vp chunk-transposed: chunk c = kflat>>3 (0..511) of 8 bf16 (16B);
// stored at Vp[(c*256 + o)*8] so a B-fragment (16 consecutive o at one chunk)
// is a 256B-coalesced load per 16-lane group.  (proven R6/R7)
// ---------------------------------------------------------------------------
__global__ __launch_bounds__(256) void kan_prep(
    const float* __restrict__ values,   // [O][D][K]
    const float* __restrict__ skip_w,   // [O][D]
    const float* __restrict__ gknots,   // [K]
    unsigned short* __restrict__ Vp)    // 2 MB bf16, chunk-transposed
{
    int tid = blockIdx.x * blockDim.x + threadIdx.x;    // 0..131071
    int e = tid * 8;
    int o = e >> 12;
    int kflat = e & 4095;
    float sw = skip_w[(o << 8) | (kflat >> 4)];
    int kmod = kflat & 15;                              // 0 or 8

    const float4* vp4 = reinterpret_cast<const float4*>(values + e);
    float4 v0 = vp4[0], v1 = vp4[1];
    float f[8] = {v0.x, v0.y, v0.z, v0.w, v1.x, v1.y, v1.z, v1.w};
    unsigned int w[4];
#pragma unroll
    for (int j = 0; j < 4; ++j) {
        float2 ab;
        ab.x = f[2*j]     + gknots[kmod + 2*j]     * sw;
        ab.y = f[2*j + 1] + gknots[kmod + 2*j + 1] * sw;
        __hip_bfloat162 p2 = __float22bfloat162_rn(ab);
        __builtin_memcpy(&w[j], &p2, 4);
    }
    size_t c = (size_t)(kflat >> 3) * 256 + (size_t)o;
    *reinterpret_cast<uint4*>(Vp + c * 8) = make_uint4(w[0], w[1], w[2], w[3]);
}

// ---------------------------------------------------------------------------
// GEMM: BM=128 x BN=128 x BK=64, 4 waves (2wm x 2wn), wave-tile 64x64.
// Pk[row][dloc] (row 0..127, dloc 0..63): u64 = (cvt_pk(1-w,w) << 16*(li&1))
//                                              | ((u64)(li>>1) << 48)
// stored at byte row*512 + ((slot ^ ((row&7)<<2))<<4) + p*8,
//   slot = kt*2 + (dloc&1), p = (dloc>>1)&1  [d = kt*4 + 2p + g].
// A-frag (mi,kh): one ds_read_b128 at (row, kt, g=lhi>>1) gives both kh;
// decode ~19 VALU per frag. Zero barriers in the K-loop.
// ---------------------------------------------------------------------------
template<int KS>
__global__ __launch_bounds__(NTHR, 2) void kan_gemm(
    const float* __restrict__ x,          // [B][D] f32
    const unsigned short* __restrict__ Vp,
    float* __restrict__ part)             // [KS][8192][256] f32
{
    __shared__ unsigned long long Pk[128 * 64];   // 64 KB

    constexpr int ITERS = 64 / KS;
    const int t    = threadIdx.x;
    const int lane = t & 63;
    const int wid  = t >> 6;
    const int wm   = wid >> 1;         // 0..1 (64 rows)
    const int wn   = wid & 1;          // 0..1 (64 cols)
    const int l15  = lane & 15;
    const int lhi  = lane >> 4;        // 0..3

    const int bid = (int)blockIdx.x;
    const int ks  = bid & (KS - 1);
    const int nt  = (bid >> 2) & 1;
    const int mt  = bid >> 3;
    const int bm0 = mt * BM;
    const int nc0 = nt * 128;
    const size_t kc0 = (size_t)ks * (512 / KS);   // global 16B-chunk base

    char* pb = (char*)&Pk[0];

    // ---- Pk build (once): thread t -> row t>>1, d-half (t&1)*32
    {
        int row = t >> 1;
        int half = (t & 1) * 32;
        const float* xr = x + (size_t)(bm0 + row) * D_DIM + ks * (256 / KS) + half;
        int rs = (row & 7) << 2;
#pragma unroll
        for (int j4 = 0; j4 < 8; ++j4) {
            float4 xv = reinterpret_cast<const float4*>(xr)[j4];
            float v[4] = {xv.x, xv.y, xv.z, xv.w};
#pragma unroll
            for (int e = 0; e < 4; ++e) {
                int dloc = half + j4 * 4 + e;
                float xc = fminf(1.f, fmaxf(-1.f, v[e]));
                float tt = (xc + 1.f) * 7.5f;        // (xc - g0)/h, h = 2/15
                int li = (int)tt;
                li = li > 14 ? 14 : li;
                float w1 = tt - (float)li;
                float2 cw; cw.x = 1.f - w1; cw.y = w1;
                __hip_bfloat162 p2 = __float22bfloat162_rn(cw);
                unsigned int pkw;
                __builtin_memcpy(&pkw, &p2, 4);
                unsigned long long q8 =
                    ((unsigned long long)pkw << ((li & 1) << 4)) |
                    ((unsigned long long)(unsigned)(li >> 1) << 48);
                int kt = dloc >> 2, p = (dloc >> 1) & 1, g = dloc & 1;
                int s = kt * 2 + g;
                *reinterpret_cast<unsigned long long*>(
                    pb + row * 512 + ((s ^ rs) << 4) + p * 8) = q8;
            }
        }
    }
    __syncthreads();   // the ONLY block-wide barrier

    // per-lane constants
    const unsigned jbase = (unsigned)((lhi & 1) * 4);  // dword window base
    const int g = lhi >> 1;                            // d-sub select
    int prow[4], prs[4];
#pragma unroll
    for (int mi = 0; mi < 4; ++mi) {
        int row = wm * 64 + mi * 16 + l15;
        prow[mi] = row * 512;
        prs[mi] = (row & 7) << 2;
    }

    // B fragment loads: frag (kh,ni): chunk kc0 + KT*8 + kh*4 + lhi,
    // col n = nc0 + wn*64 + ni*16 + l15.
    #define LOADB(BG, KT)                                                      \
        {                                                                      \
            const unsigned short* _b = Vp + (kc0 + (size_t)(KT) * 8) * 2048;   \
            _Pragma("unroll")                                                  \
            for (int kh = 0; kh < 2; ++kh)                                     \
                _Pragma("unroll")                                              \
                for (int ni = 0; ni < 4; ++ni) {                               \
                    int n = nc0 + wn * 64 + ni * 16 + l15;                     \
                    BG[kh * 4 + ni] = *reinterpret_cast<const bf16x8*>(        \
                        _b + ((size_t)((kh * 4 + lhi) * 256 + n)) * 8);        \
                }                                                              \
        }

    // decode one (lo,hi) -> 4-dword fragment window
    auto mkfrag = [&](unsigned lo, unsigned hi) -> bf16x8 {
        unsigned jd = (hi >> 16) - jbase;
        unsigned hc = hi & 0xffffu;
        uint4 w;
        w.x = (jd == 0u) ? lo : ((jd + 1u == 0u) ? hc : 0u);
        w.y = (jd == 1u) ? lo : ((jd == 0u) ? hc : 0u);
        w.z = (jd == 2u) ? lo : ((jd == 1u) ? hc : 0u);
        w.w = (jd == 3u) ? lo : ((jd == 2u) ? hc : 0u);
        bf16x8 r;
        __builtin_memcpy(&r, &w, 16);
        return r;
    };

    f32x4 acc[4][4] = {};
    bf16x8 bgA[8], bgB[8];

    LOADB(bgA, 0);

    #define ITERBODY(KT, BGC, BGN)                                            \
        {                                                                     \
            const bool last = (KT) == ITERS - 1;                              \
            if (!last) LOADB(BGN, (KT) + 1);                                  \
            uint4 q[4];                                                       \
            _Pragma("unroll")                                                 \
            for (int mi = 0; mi < 4; ++mi)                                    \
                q[mi] = *reinterpret_cast<const uint4*>(                      \
                    pb + prow[mi] + ((((KT) * 2 + g) ^ prs[mi]) << 4));       \
            bf16x8 af[4];                                                     \
            _Pragma("unroll")                                                 \
            for (int mi = 0; mi < 4; ++mi)                                    \
                af[mi] = mkfrag(q[mi].x, q[mi].y);                            \
            __builtin_amdgcn_s_setprio(1);                                    \
            _Pragma("unroll")                                                 \
            for (int mi = 0; mi < 4; ++mi)                                    \
                _Pragma("unroll")                                             \
                for (int ni = 0; ni < 4; ++ni)                                \
                    acc[mi][ni] = __builtin_amdgcn_mfma_f32_16x16x32_bf16(    \
                        af[mi], BGC[ni], acc[mi][ni], 0, 0, 0);               \
            __builtin_amdgcn_s_setprio(0);                                    \
            _Pragma("unroll")                                                 \
            for (int mi = 0; mi < 4; ++mi)                                    \
                af[mi] = mkfrag(q[mi].z, q[mi].w);                            \
            __builtin_amdgcn_s_setprio(1);                                    \
            _Pragma("unroll")                                                 \
            for (int mi = 0; mi < 4; ++mi)                                    \
                _Pragma("unroll")                                             \
                for (int ni = 0; ni < 4; ++ni)                                \
                    acc[mi][ni] = __builtin_amdgcn_mfma_f32_16x16x32_bf16(    \
                        af[mi], BGC[4 + ni], acc[mi][ni], 0, 0, 0);           \
            __builtin_amdgcn_s_setprio(0);                                    \
        }

    for (int t2 = 0; t2 < ITERS / 2; ++t2) {
        ITERBODY(2 * t2,     bgA, bgB);
        ITERBODY(2 * t2 + 1, bgB, bgA);
    }
    #undef ITERBODY
    #undef LOADB

    // ---- epilogue: partial store (bias added in reduce)
    float* dst = part + (size_t)ks * (8192 * 256);
#pragma unroll
    for (int ni = 0; ni < 4; ++ni) {
        int col = nc0 + wn * 64 + ni * 16 + l15;
#pragma unroll
        for (int mi = 0; mi < 4; ++mi) {
            f32x4 v = acc[mi][ni];
            int row0 = bm0 + wm * 64 + mi * 16 + lhi * 4;
#pragma unroll
            for (int r = 0; r < 4; ++r)
                dst[(size_t)(row0 + r) * O_DIM + col] = v[r];
        }
    }
}

// ---------------------------------------------------------------------------
// Reduce: out = sum_p part[p] + skip_b  (vectorized f32x4)
// ---------------------------------------------------------------------------
__global__ __launch_bounds__(256) void kan_reduce(
    const float* __restrict__ part,   // [nparts][8192][256]
    const float* __restrict__ skip_b, // [256]
    float* __restrict__ out,          // [8192][256]
    int nparts)
{
    size_t i4 = (size_t)blockIdx.x * 256 + threadIdx.x;   // float4 index
    size_t e = i4 * 4;
    f32x4 s = *reinterpret_cast<const f32x4*>(&skip_b[e & 255]);
    for (int p = 0; p < nparts; ++p)
        s += *reinterpret_cast<const f32x4*>(part + (size_t)p * (8192 * 256) + e);
    *reinterpret_cast<f32x4*>(out + e) = s;
}

// ---------------------------------------------------------------------------
// Naive fallback (only if workspace is unexpectedly small) — correct, slow.
// ---------------------------------------------------------------------------
__global__ __launch_bounds__(256) void kan_naive(
    const float* __restrict__ x,
    const unsigned short* __restrict__ Vp,   // chunk-transposed
    const float* __restrict__ skip_b,
    float* __restrict__ out)
{
    int b = blockIdx.x, o = threadIdx.x;
    float acc = skip_b[o];
    for (int d = 0; d < 256; ++d) {
        float xc = fminf(1.f, fmaxf(-1.f, x[(size_t)b * 256 + d]));
        float tt = (xc + 1.f) * 7.5f;
        int li = (int)tt; li = li > 14 ? 14 : li;
        float w1 = tt - (float)li;
        int k0 = d * 16 + li;
        unsigned short u0 = Vp[((size_t)(k0 >> 3) * 256 + o) * 8 + (k0 & 7)];
        int k1 = k0 + 1;
        unsigned short u1 = Vp[((size_t)(k1 >> 3) * 256 + o) * 8 + (k1 & 7)];
        float f0 = __uint_as_float((unsigned)u0 << 16);
        float f1 = __uint_as_float((unsigned)u1 << 16);
        acc += (1.f - w1) * f0 + w1 * f1;
    }
    out[(size_t)b * 256 + o] = acc;
}

extern "C" void kernel_launch(void* const* d_in, const int* in_sizes, int n_in,
                              void* d_out, int out_size, void* d_ws, size_t ws_size,
                              hipStream_t stream) {
    const float* x      = (const float*)d_in[0];   // [8192][256]
    const float* values = (const float*)d_in[1];   // [256][256][16]
    const float* skip_w = (const float*)d_in[2];   // [256][256]
    const float* skip_b = (const float*)d_in[3];   // [256]
    const float* gknots = (const float*)d_in[4];   // [16]
    float* out = (float*)d_out;
    (void)in_sizes; (void)n_in; (void)out_size;

    unsigned short* Vp = (unsigned short*)d_ws;                    // 2 MB
    float* part = (float*)((char*)d_ws + 2 * 1024 * 1024);         // 32 MB

    kan_prep<<<dim3(512), dim3(256), 0, stream>>>(values, skip_w, gknots, Vp);

    const size_t need = 2u * 1024 * 1024 + (size_t)4 * 8192 * 256 * 4;
    if (ws_size >= need) {
        // 64 mt x 2 nt x 4 ks = 512 blocks (2/CU); XCD = (nt*4+ks)%8 ->
        // each XCD owns one (nt,ks): its Vp slice + x slice stay L2-local.
        kan_gemm<4><<<dim3(512), dim3(NTHR), 0, stream>>>(x, Vp, part);
        kan_reduce<<<dim3(2048), dim3(256), 0, stream>>>(part, skip_b, out, 4);
    } else {
        kan_naive<<<dim3(8192), dim3(256), 0, stream>>>(x, Vp, skip_b, out);
    }
}